// Round 16
// baseline (105.888 us; speedup 1.0000x reference)
//
#include <hip/hip_runtime.h>
#include <hip/hip_bf16.h>

// Problem constants
#define B_ 4
#define S_ 4096
#define D_ 1024
#define E_ 8
#define H_ 128
#define M_ (B_*S_)   // 16384 tokens
#define K_ 1024
#define N_ 1024      // E_*H_ == D_ == 1024
#define NT_ (K_/64)  // 16 K-tiles of BK=64
#define NIT_ (NT_/2) // 8 iterations, 2 K-tiles each

typedef short bf16x8 __attribute__((ext_vector_type(8)));
typedef float f32x4 __attribute__((ext_vector_type(4)));

__device__ __forceinline__ unsigned short f2bf(float f){
  union { float f; unsigned int u; } v; v.f = f;
  unsigned int u = v.u;
  unsigned int r = (u + 0x7fffu + ((u >> 16) & 1u)) >> 16;  // RNE
  return (unsigned short)r;
}

__device__ __forceinline__ void gload16(const void* g, void* l){
  __builtin_amdgcn_global_load_lds((const __attribute__((address_space(1))) void*)g,
                                   (__attribute__((address_space(3))) void*)l, 16, 0, 0);
}

// ---------------------------------------------------------------------------
// Kernel 1 (R8-proven, split launch): x -> xb (bf16) + gate softmax.
// ---------------------------------------------------------------------------
__global__ __launch_bounds__(256)
void prep_x_gate(const float* __restrict__ x, const float* __restrict__ Wg,
                 const float* __restrict__ bg, unsigned short* __restrict__ xb,
                 float* __restrict__ gate){
  int tid = threadIdx.x;
  int lane = tid & 63;
  int m = blockIdx.x * 4 + (tid >> 6);
  const float* xr = x + (size_t)m * D_;
  unsigned short* xbr = xb + (size_t)m * D_;
  float acc[E_];
  #pragma unroll
  for (int e = 0; e < E_; ++e) acc[e] = 0.f;
  #pragma unroll
  for (int c = 0; c < D_/64; ++c){
    int d = c*64 + lane;
    float xs = xr[d];
    xbr[d] = f2bf(xs);
    const float4 w0 = *(const float4*)(Wg + (size_t)d * E_);
    const float4 w1 = *(const float4*)(Wg + (size_t)d * E_ + 4);
    acc[0] = fmaf(xs, w0.x, acc[0]); acc[1] = fmaf(xs, w0.y, acc[1]);
    acc[2] = fmaf(xs, w0.z, acc[2]); acc[3] = fmaf(xs, w0.w, acc[3]);
    acc[4] = fmaf(xs, w1.x, acc[4]); acc[5] = fmaf(xs, w1.y, acc[5]);
    acc[6] = fmaf(xs, w1.z, acc[6]); acc[7] = fmaf(xs, w1.w, acc[7]);
  }
  #pragma unroll
  for (int off = 32; off > 0; off >>= 1){
    #pragma unroll
    for (int e = 0; e < E_; ++e) acc[e] += __shfl_xor(acc[e], off, 64);
  }
  float lg[E_]; float mx = -1e30f;
  #pragma unroll
  for (int e = 0; e < E_; ++e){ lg[e] = acc[e] + bg[e]; mx = fmaxf(mx, lg[e]); }
  float s = 0.f;
  #pragma unroll
  for (int e = 0; e < E_; ++e){ lg[e] = expf(lg[e] - mx); s += lg[e]; }
  float inv = 1.f / s;
  if (lane < E_) gate[(size_t)m * E_ + lane] = lg[lane] * inv;
}

// ---------------------------------------------------------------------------
// Kernel 2: per-expert transpose+pack f32 -> bf16, n-major/k-contiguous.
// ---------------------------------------------------------------------------
__global__ __launch_bounds__(256)
void transpose_pack(const float* __restrict__ in, unsigned short* __restrict__ out,
                    int C, int ostride, int in_estride, int out_ebase){
  __shared__ float t[32][33];
  int e = blockIdx.z;
  const float* ip = in + (size_t)e * in_estride;
  unsigned short* op = out + (size_t)e * out_ebase;
  int tx = threadIdx.x, ty = threadIdx.y;   // 32 x 8
  int c0 = blockIdx.x * 32, r0 = blockIdx.y * 32;
  #pragma unroll
  for (int yy = 0; yy < 32; yy += 8)
    t[ty + yy][tx] = ip[(size_t)(r0 + ty + yy) * C + (c0 + tx)];
  __syncthreads();
  #pragma unroll
  for (int yy = 0; yy < 32; yy += 8)
    op[(size_t)(c0 + ty + yy) * ostride + (r0 + tx)] = f2bf(t[tx][ty + yy]);
}

// ---------------- shared GEMM macros (256x256, BK=64, 8-wave, 4-phase) ------
#define READ_A(b,r) do{ int ab_ = (b)*16384 + abase0; \
  _Pragma("unroll") for (int f2 = 0; f2 < 4; ++f2){ \
    af[f2][0] = *(const bf16x8*)&lds[ab_ + ((r)*4+f2)*1024 + bk0]; \
    af[f2][1] = *(const bf16x8*)&lds[ab_ + ((r)*4+f2)*1024 + bk1]; } }while(0)
#define READ_B(b,c) do{ int bb_ = (b)*16384 + bbase0; \
  _Pragma("unroll") for (int j2 = 0; j2 < 2; ++j2){ \
    bfr[(c)*2+j2][0] = *(const bf16x8*)&lds[bb_ + ((c)*2+j2)*1024 + bk0]; \
    bfr[(c)*2+j2][1] = *(const bf16x8*)&lds[bb_ + ((c)*2+j2)*1024 + bk1]; } }while(0)
#define MFMA16(r,c) do{ \
  _Pragma("unroll") for (int f2 = 0; f2 < 4; ++f2) \
  _Pragma("unroll") for (int j2 = 0; j2 < 2; ++j2){ \
    acc[(r)*4+f2][(c)*2+j2] = __builtin_amdgcn_mfma_f32_16x16x32_bf16(af[f2][0], bfr[(c)*2+j2][0], acc[(r)*4+f2][(c)*2+j2], 0,0,0); \
    acc[(r)*4+f2][(c)*2+j2] = __builtin_amdgcn_mfma_f32_16x16x32_bf16(af[f2][1], bfr[(c)*2+j2][1], acc[(r)*4+f2][(c)*2+j2], 0,0,0); \
  } }while(0)
// PH_MID: drain own-wave LDS reads BEFORE the barrier. Then, when any wave
// exits barrier P, ALL waves' phase-P ds_reads have completed — so phase-P+1
// stage DMAs can never overwrite a still-being-read region. This converts the
// 1-barrier WAR separation from a timing assumption (R15's replay race) into
// an architectural guarantee. MFMA then issues wait-free after the barrier.
#define PH_MID  asm volatile("s_waitcnt lgkmcnt(0)" ::: "memory"); \
                __builtin_amdgcn_s_barrier(); \
                __builtin_amdgcn_s_setprio(1)
#define PH_END  __builtin_amdgcn_s_setprio(0)
#define VMW(N)  asm volatile("s_waitcnt vmcnt(" #N ")" ::: "memory")

// ---------------------------------------------------------------------------
// Kernel 3: 256x256-tile, BK=64, 8-wave, 4-phase bf16 GEMM (R13 schedule,
// WAR-hardened PH_MID). vmcnt ledger (validated R11/R13/R14):
//   prologue: t0 full (8) + t1 {B,Ah0} (6), VMW(6) -> buf0 published.
//   Q1: SA(1,1,kt1); Q2: SB(0,*,ktn0), VMW(4) [final: VMW(0)] -> buf1 pub;
//   Q3: SA(0,*,ktn0); Q4: SB(1,*,ktn1)+SA(1,0,ktn1), VMW(6) -> buf0 pub.
// PASS 1: staged-LDS coalesced bf16 epilogue, gate*relu(acc+b1).
// PASS 2: direct f32 stores, acc + sum_e gate_e*b2[e][d].
// ---------------------------------------------------------------------------
template<int PASS>
__global__ __launch_bounds__(512, 2)
void gemm_moe8(const unsigned short* __restrict__ A,
               const unsigned short* __restrict__ Bt,
               const float* __restrict__ gate,
               const float* __restrict__ bias,
               void* __restrict__ outp)
{
  __shared__ unsigned short lds[65536];   // 128 KiB

  int bid = blockIdx.x;
  int xcd = bid & 7, pos = bid >> 3;
  int mb = xcd * 8 + (pos >> 2);
  int nb = pos & 3;
  int m0 = mb * 256, n0 = nb * 256;

  int tid = threadIdx.x;
  int lane = tid & 63;
  int w = tid >> 6;
  int wm = w & 1, wn = w >> 1;            // 2x4 wave grid; wave owns 128x64
  int rowi = lane & 15, s4 = lane >> 4;

  // staging addresses (linear LDS dest; swizzled global source)
  int sg = (tid & 7) ^ ((tid >> 3) & 7);
  const unsigned short* gA = A  + (size_t)(m0 + (tid >> 3)) * K_ + sg * 8;
  const unsigned short* gB = Bt + (size_t)(n0 + (tid >> 3)) * K_ + sg * 8;
  int t8 = tid * 8;

#define STAGE_A(b,h,kt) do{ const unsigned short* g_ = gA + (size_t)((h)*128)*K_ + (kt)*64; \
  gload16(g_,                 &lds[(b)*16384 + (h)*8192 + t8]); \
  gload16(g_ + (size_t)64*K_, &lds[(b)*16384 + (h)*8192 + t8 + 4096]); }while(0)
#define STAGE_B(b,h,kt) do{ const unsigned short* g_ = gB + (size_t)((h)*128)*K_ + (kt)*64; \
  gload16(g_,                 &lds[32768 + (b)*16384 + (h)*8192 + t8]); \
  gload16(g_ + (size_t)64*K_, &lds[32768 + (b)*16384 + (h)*8192 + t8 + 4096]); }while(0)

  // read-side fragment offsets (same XOR on the slot)
  int bk0 = rowi*64 + (( s4     ) ^ (rowi & 7)) * 8;
  int bk1 = rowi*64 + ((4 + s4  ) ^ (rowi & 7)) * 8;
  int abase0 = wm * 8192;
  int bbase0 = 32768 + (wn >> 1) * 8192 + (wn & 1) * 4096;

  f32x4 acc[8][4];
  #pragma unroll
  for (int i = 0; i < 8; ++i){
    #pragma unroll
    for (int j = 0; j < 4; ++j){ f32x4 z = {0.f,0.f,0.f,0.f}; acc[i][j] = z; }
  }
  bf16x8 af[4][2], bfr[4][2];

  // prologue: tile0 full; tile1 {Bh0,Bh1,Ah0} in flight (counted wait)
  STAGE_B(0,0,0); STAGE_B(0,1,0);
  STAGE_A(0,0,0); STAGE_A(0,1,0);
  STAGE_B(1,0,1); STAGE_B(1,1,1);
  STAGE_A(1,0,1);
  VMW(6);
  __builtin_amdgcn_s_barrier();           // publishes buf0; 6 in flight

  #pragma unroll 1
  for (int it = 0; it < NIT_; ++it){
    int kt1  = 2*it + 1;
    int ktn0 = 2*it + 2, ktn1 = 2*it + 3;
    bool more = (it < NIT_ - 1);
    // Q1 — buf0, rows 0-3; reads in consumption order (bfr01 first)
    READ_B(0,0); READ_A(0,0); READ_B(0,1);
    STAGE_A(1,1,kt1);
    PH_MID; MFMA16(0,0); MFMA16(0,1); PH_END;
    // Q2 — buf0, rows 4-7 (bfr already in regs); barrier publishes buf1
    READ_A(0,1);
    if (more){ STAGE_B(0,0,ktn0); STAGE_B(0,1,ktn0); VMW(4); }
    else     { VMW(0); }
    PH_MID; MFMA16(1,0); MFMA16(1,1); PH_END;
    // Q3 — buf1, rows 0-3; reads in consumption order
    READ_B(1,0); READ_A(1,0); READ_B(1,1);
    if (more){ STAGE_A(0,0,ktn0); STAGE_A(0,1,ktn0); }
    PH_MID; MFMA16(0,0); MFMA16(0,1); PH_END;
    // Q4 — buf1, rows 4-7; barrier publishes buf0 for next Q1
    READ_A(1,1);
    if (more){ STAGE_B(1,0,ktn1); STAGE_B(1,1,ktn1); STAGE_A(1,0,ktn1); }
    VMW(6);
    PH_MID; MFMA16(1,1); MFMA16(1,0); PH_END;
  }

  int ncol0 = n0 + wn*64;
  if (PASS == 1){
    // staged-LDS coalesced bf16 epilogue (wave-private 16 KB region)
    asm volatile("s_waitcnt lgkmcnt(0)" ::: "memory");
    __builtin_amdgcn_s_barrier();
    unsigned short* Hp = (unsigned short*)outp;
    float* lws = (float*)lds + w * 4096;   // 64 rows x 64 cols f32
    int e = nb*2 + (wn >> 1);              // wave's 64-col range = one expert
    float b1v[4];
    #pragma unroll
    for (int j = 0; j < 4; ++j) b1v[j] = bias[e*H_ + (wn&1)*64 + j*16 + rowi];
    #pragma unroll
    for (int ci = 0; ci < 2; ++ci){
      #pragma unroll
      for (int f2 = 0; f2 < 4; ++f2){
        int fi = ci*4 + f2;
        #pragma unroll
        for (int jj = 0; jj < 4; ++jj){
          int m = m0 + wm*128 + fi*16 + s4*4 + jj;
          float g = gate[(size_t)m*E_ + e];
          int r_l = f2*16 + s4*4 + jj;
          #pragma unroll
          for (int j = 0; j < 4; ++j){
            float v = fmaxf(acc[fi][j][jj] + b1v[j], 0.f) * g;
            lws[r_l*64 + ((j*16 + rowi) ^ (s4 << 4))] = v;
          }
        }
      }
      asm volatile("s_waitcnt lgkmcnt(0)" ::: "memory");
      #pragma unroll
      for (int it2 = 0; it2 < 16; ++it2){
        int r_l = it2*4 + (lane >> 4);
        int c4  = lane & 15;
        int X2  = it2 & 3;                 // == (r_l>>2)&3, uniform per instr
        f32x4 v = *(const f32x4*)&lws[r_l*64 + ((c4*4) ^ (X2 << 4))];
        union { unsigned short us[4]; uint2 u2; } pk;
        #pragma unroll
        for (int q = 0; q < 4; ++q) pk.us[q] = f2bf(v[q]);
        int m = m0 + wm*128 + ci*64 + r_l;
        *(uint2*)&Hp[(size_t)m*N_ + ncol0 + c4*4] = pk.u2;
      }
      if (ci == 0) asm volatile("s_waitcnt lgkmcnt(0)" ::: "memory");
    }
  } else {
    // direct f32 epilogue (R3 form — 64B j-chunks merge into full lines)
    float* Out = (float*)outp;
    float b2v[8][4];
    #pragma unroll
    for (int j = 0; j < 4; ++j){
      int n = ncol0 + j*16 + rowi;
      #pragma unroll
      for (int e = 0; e < 8; ++e) b2v[e][j] = bias[(size_t)e*N_ + n];
    }
    #pragma unroll
    for (int fi = 0; fi < 8; ++fi){
      #pragma unroll
      for (int jj = 0; jj < 4; ++jj){
        int m = m0 + wm*128 + fi*16 + s4*4 + jj;
        const float4 g0 = *(const float4*)(gate + (size_t)m*E_);
        const float4 g1 = *(const float4*)(gate + (size_t)m*E_ + 4);
        float bv[4];
        #pragma unroll
        for (int j = 0; j < 4; ++j)
          bv[j] = g0.x*b2v[0][j] + g0.y*b2v[1][j] + g0.z*b2v[2][j] + g0.w*b2v[3][j]
                + g1.x*b2v[4][j] + g1.y*b2v[5][j] + g1.z*b2v[6][j] + g1.w*b2v[7][j];
        #pragma unroll
        for (int j = 0; j < 4; ++j)
          Out[(size_t)m*N_ + ncol0 + j*16 + rowi] = acc[fi][j][jj] + bv[j];
      }
    }
  }
#undef STAGE_A
#undef STAGE_B
}

// ---------------------------------------------------------------------------
extern "C" void kernel_launch(void* const* d_in, const int* in_sizes, int n_in,
                              void* d_out, int out_size, void* d_ws, size_t ws_size,
                              hipStream_t stream){
  const float* x  = (const float*)d_in[0];
  const float* W1 = (const float*)d_in[1];
  const float* b1 = (const float*)d_in[2];
  const float* W2 = (const float*)d_in[3];
  const float* b2 = (const float*)d_in[4];
  const float* Wg = (const float*)d_in[5];
  const float* bg = (const float*)d_in[6];
  float* out = (float*)d_out;

  char* ws = (char*)d_ws;
  unsigned short* xb  = (unsigned short*)(ws);                         // 32 MB bf16 x
  unsigned short* Hp  = (unsigned short*)(ws + ((size_t)32<<20));      // 32 MB bf16 H'
  unsigned short* B1T = (unsigned short*)(ws + ((size_t)64<<20));      // 2 MB
  unsigned short* B2T = (unsigned short*)(ws + ((size_t)66<<20));      // 2 MB
  float*          gate= (float*)(ws + ((size_t)68<<20));               // 512 KB

  hipLaunchKernelGGL(prep_x_gate, dim3(M_/4), dim3(256), 0, stream, x, Wg, bg, xb, gate);
  hipLaunchKernelGGL(transpose_pack, dim3(128/32, 1024/32, 8), dim3(32,8), 0, stream,
                     W1, B1T, 128, 1024, 1024*128, 128*1024);
  hipLaunchKernelGGL(transpose_pack, dim3(1024/32, 128/32, 8), dim3(32,8), 0, stream,
                     W2, B2T, 1024, 1024, 128*1024, 128);
  hipLaunchKernelGGL((gemm_moe8<1>), dim3(256), dim3(512), 0, stream,
                     xb, B1T, gate, b1, (void*)Hp);
  hipLaunchKernelGGL((gemm_moe8<2>), dim3(256), dim3(512), 0, stream,
                     Hp, B2T, gate, b2, (void*)out);
}

// Round 17
// 104.894 us; speedup vs baseline: 1.0095x; 1.0095x over previous
//
#include <hip/hip_runtime.h>
#include <hip/hip_bf16.h>

// Problem constants
#define B_ 4
#define S_ 4096
#define D_ 1024
#define E_ 8
#define H_ 128
#define M_ (B_*S_)   // 16384 tokens
#define K_ 1024
#define N_ 1024      // E_*H_ == D_ == 1024
#define NT_ (K_/64)  // 16 K-tiles of BK=64
#define NIT_ (NT_/2) // 8 iterations, 2 K-tiles each

typedef short bf16x8 __attribute__((ext_vector_type(8)));
typedef float f32x4 __attribute__((ext_vector_type(4)));

__device__ __forceinline__ unsigned short f2bf(float f){
  union { float f; unsigned int u; } v; v.f = f;
  unsigned int u = v.u;
  unsigned int r = (u + 0x7fffu + ((u >> 16) & 1u)) >> 16;  // RNE
  return (unsigned short)r;
}

__device__ __forceinline__ void gload16(const void* g, void* l){
  __builtin_amdgcn_global_load_lds((const __attribute__((address_space(1))) void*)g,
                                   (__attribute__((address_space(3))) void*)l, 16, 0, 0);
}

// ---------------------------------------------------------------------------
// Kernel 1 (R8-proven): x -> xb (bf16) + gate softmax, 1 token/wave.
// ---------------------------------------------------------------------------
__global__ __launch_bounds__(256)
void prep_x_gate(const float* __restrict__ x, const float* __restrict__ Wg,
                 const float* __restrict__ bg, unsigned short* __restrict__ xb,
                 float* __restrict__ gate){
  int tid = threadIdx.x;
  int lane = tid & 63;
  int m = blockIdx.x * 4 + (tid >> 6);
  const float* xr = x + (size_t)m * D_;
  unsigned short* xbr = xb + (size_t)m * D_;
  float acc[E_];
  #pragma unroll
  for (int e = 0; e < E_; ++e) acc[e] = 0.f;
  #pragma unroll
  for (int c = 0; c < D_/64; ++c){
    int d = c*64 + lane;
    float xs = xr[d];
    xbr[d] = f2bf(xs);
    const float4 w0 = *(const float4*)(Wg + (size_t)d * E_);
    const float4 w1 = *(const float4*)(Wg + (size_t)d * E_ + 4);
    acc[0] = fmaf(xs, w0.x, acc[0]); acc[1] = fmaf(xs, w0.y, acc[1]);
    acc[2] = fmaf(xs, w0.z, acc[2]); acc[3] = fmaf(xs, w0.w, acc[3]);
    acc[4] = fmaf(xs, w1.x, acc[4]); acc[5] = fmaf(xs, w1.y, acc[5]);
    acc[6] = fmaf(xs, w1.z, acc[6]); acc[7] = fmaf(xs, w1.w, acc[7]);
  }
  #pragma unroll
  for (int off = 32; off > 0; off >>= 1){
    #pragma unroll
    for (int e = 0; e < E_; ++e) acc[e] += __shfl_xor(acc[e], off, 64);
  }
  float lg[E_]; float mx = -1e30f;
  #pragma unroll
  for (int e = 0; e < E_; ++e){ lg[e] = acc[e] + bg[e]; mx = fmaxf(mx, lg[e]); }
  float s = 0.f;
  #pragma unroll
  for (int e = 0; e < E_; ++e){ lg[e] = expf(lg[e] - mx); s += lg[e]; }
  float inv = 1.f / s;
  if (lane < E_) gate[(size_t)m * E_ + lane] = lg[lane] * inv;
}

// ---------------------------------------------------------------------------
// Kernel 2: per-expert transpose+pack f32 -> bf16, n-major/k-contiguous.
// ---------------------------------------------------------------------------
__global__ __launch_bounds__(256)
void transpose_pack(const float* __restrict__ in, unsigned short* __restrict__ out,
                    int C, int ostride, int in_estride, int out_ebase){
  __shared__ float t[32][33];
  int e = blockIdx.z;
  const float* ip = in + (size_t)e * in_estride;
  unsigned short* op = out + (size_t)e * out_ebase;
  int tx = threadIdx.x, ty = threadIdx.y;   // 32 x 8
  int c0 = blockIdx.x * 32, r0 = blockIdx.y * 32;
  #pragma unroll
  for (int yy = 0; yy < 32; yy += 8)
    t[ty + yy][tx] = ip[(size_t)(r0 + ty + yy) * C + (c0 + tx)];
  __syncthreads();
  #pragma unroll
  for (int yy = 0; yy < 32; yy += 8)
    op[(size_t)(c0 + ty + yy) * ostride + (r0 + tx)] = f2bf(t[tx][ty + yy]);
}

// ---------------- shared GEMM macros (256x256, BK=64, 8-wave, 4-phase) ------
#define READ_A(b,r) do{ int ab_ = (b)*16384 + abase0; \
  _Pragma("unroll") for (int f2 = 0; f2 < 4; ++f2){ \
    af[f2][0] = *(const bf16x8*)&lds[ab_ + ((r)*4+f2)*1024 + bk0]; \
    af[f2][1] = *(const bf16x8*)&lds[ab_ + ((r)*4+f2)*1024 + bk1]; } }while(0)
#define READ_B(b,c) do{ int bb_ = (b)*16384 + bbase0; \
  _Pragma("unroll") for (int j2 = 0; j2 < 2; ++j2){ \
    bfr[(c)*2+j2][0] = *(const bf16x8*)&lds[bb_ + ((c)*2+j2)*1024 + bk0]; \
    bfr[(c)*2+j2][1] = *(const bf16x8*)&lds[bb_ + ((c)*2+j2)*1024 + bk1]; } }while(0)
#define MFMA16(r,c) do{ \
  _Pragma("unroll") for (int f2 = 0; f2 < 4; ++f2) \
  _Pragma("unroll") for (int j2 = 0; j2 < 2; ++j2){ \
    acc[(r)*4+f2][(c)*2+j2] = __builtin_amdgcn_mfma_f32_16x16x32_bf16(af[f2][0], bfr[(c)*2+j2][0], acc[(r)*4+f2][(c)*2+j2], 0,0,0); \
    acc[(r)*4+f2][(c)*2+j2] = __builtin_amdgcn_mfma_f32_16x16x32_bf16(af[f2][1], bfr[(c)*2+j2][1], acc[(r)*4+f2][(c)*2+j2], 0,0,0); \
  } }while(0)
#define PH_MID  __builtin_amdgcn_s_barrier(); \
                __builtin_amdgcn_s_setprio(1)
#define PH_END  __builtin_amdgcn_s_setprio(0)
#define VMW(N)  asm volatile("s_waitcnt vmcnt(" #N ")" ::: "memory")

// ---------------------------------------------------------------------------
// Kernel 3: 256x256-tile, BK=64, 8-wave, 4-phase bf16 GEMM — RACE-FIXED.
// R17 change vs R13: both buf1.A half-stages moved into Q1. This removes the
// SAME-PHASE WAR of R11-R15 (Q4 staged buf1.h0 while Q4's own READ_A(1,1)
// read part of that region — zero-barrier race; fired in R15's replay).
// Now every phase's stage region is disjoint from that phase's reads, and
// every stage is >=1 barrier after its region's last read (reads are
// register-consumed by the MFMA immediately after their barrier, while the
// overwriting DMA lands >= one MFMA cluster + ~300cy later).
// Stage map: Q1: SA(1,0,kt1)+SA(1,1,kt1) | Q2: SB(0,*,ktn0), VMW(4|0) -> pub
// buf1 | Q3: SA(0,*,ktn0) | Q4: SB(1,*,ktn1), VMW(4) -> pub buf0.
// Ledger (steady, 4 ops/phase): Q2's VMW(4) drains prevQ4.SB+Q1.SA = buf1;
// Q4's VMW(4) drains Q2.SB+Q3.SA = buf0. Final iter: Q2 VMW(0), rest trivial.
// Prologue: t0 full (8) + t1.B (4), VMW(4) -> buf0 published.
// PASS 1: staged-LDS coalesced bf16 epilogue, gate*relu(acc+b1).
// PASS 2: direct f32 stores, acc + sum_e gate_e*b2[e][d].
// ---------------------------------------------------------------------------
template<int PASS>
__global__ __launch_bounds__(512, 2)
void gemm_moe8(const unsigned short* __restrict__ A,
               const unsigned short* __restrict__ Bt,
               const float* __restrict__ gate,
               const float* __restrict__ bias,
               void* __restrict__ outp)
{
  __shared__ unsigned short lds[65536];   // 128 KiB

  int bid = blockIdx.x;
  int xcd = bid & 7, pos = bid >> 3;
  int mb = xcd * 8 + (pos >> 2);
  int nb = pos & 3;
  int m0 = mb * 256, n0 = nb * 256;

  int tid = threadIdx.x;
  int lane = tid & 63;
  int w = tid >> 6;
  int wm = w & 1, wn = w >> 1;            // 2x4 wave grid; wave owns 128x64
  int rowi = lane & 15, s4 = lane >> 4;

  // staging addresses (linear LDS dest; swizzled global source)
  int sg = (tid & 7) ^ ((tid >> 3) & 7);
  const unsigned short* gA = A  + (size_t)(m0 + (tid >> 3)) * K_ + sg * 8;
  const unsigned short* gB = Bt + (size_t)(n0 + (tid >> 3)) * K_ + sg * 8;
  int t8 = tid * 8;

#define STAGE_A(b,h,kt) do{ const unsigned short* g_ = gA + (size_t)((h)*128)*K_ + (kt)*64; \
  gload16(g_,                 &lds[(b)*16384 + (h)*8192 + t8]); \
  gload16(g_ + (size_t)64*K_, &lds[(b)*16384 + (h)*8192 + t8 + 4096]); }while(0)
#define STAGE_B(b,h,kt) do{ const unsigned short* g_ = gB + (size_t)((h)*128)*K_ + (kt)*64; \
  gload16(g_,                 &lds[32768 + (b)*16384 + (h)*8192 + t8]); \
  gload16(g_ + (size_t)64*K_, &lds[32768 + (b)*16384 + (h)*8192 + t8 + 4096]); }while(0)

  // read-side fragment offsets (same XOR on the slot)
  int bk0 = rowi*64 + (( s4     ) ^ (rowi & 7)) * 8;
  int bk1 = rowi*64 + ((4 + s4  ) ^ (rowi & 7)) * 8;
  int abase0 = wm * 8192;
  int bbase0 = 32768 + (wn >> 1) * 8192 + (wn & 1) * 4096;

  f32x4 acc[8][4];
  #pragma unroll
  for (int i = 0; i < 8; ++i){
    #pragma unroll
    for (int j = 0; j < 4; ++j){ f32x4 z = {0.f,0.f,0.f,0.f}; acc[i][j] = z; }
  }
  bf16x8 af[4][2], bfr[4][2];

  // prologue: tile0 full (8 loads) + tile1.B (4 loads); buf1.A comes in Q1.
  STAGE_B(0,0,0); STAGE_B(0,1,0);
  STAGE_A(0,0,0); STAGE_A(0,1,0);
  STAGE_B(1,0,1); STAGE_B(1,1,1);
  VMW(4);
  __builtin_amdgcn_s_barrier();           // publishes buf0; t1.B in flight

  #pragma unroll 1
  for (int it = 0; it < NIT_; ++it){
    int kt1  = 2*it + 1;
    int ktn0 = 2*it + 2, ktn1 = 2*it + 3;
    bool more = (it < NIT_ - 1);
    // Q1 — buf0, rows 0-3; stages BOTH buf1.A halves (last read prev Q3/Q4)
    READ_B(0,0); READ_A(0,0); READ_B(0,1);
    STAGE_A(1,0,kt1); STAGE_A(1,1,kt1);
    PH_MID; MFMA16(0,0); MFMA16(0,1); PH_END;
    // Q2 — buf0 rows 4-7 (A-region read; stages B-region: disjoint);
    //      VMW publishes buf1 at this barrier
    READ_A(0,1);
    if (more){ STAGE_B(0,0,ktn0); STAGE_B(0,1,ktn0); VMW(4); }
    else     { VMW(0); }
    PH_MID; MFMA16(1,0); MFMA16(1,1); PH_END;
    // Q3 — buf1, rows 0-3; stages buf0.A (disjoint buffer)
    READ_B(1,0); READ_A(1,0); READ_B(1,1);
    if (more){ STAGE_A(0,0,ktn0); STAGE_A(0,1,ktn0); }
    PH_MID; MFMA16(0,0); MFMA16(0,1); PH_END;
    // Q4 — buf1 rows 4-7 (A-region read; stages B-region: disjoint);
    //      VMW publishes buf0 at this barrier
    READ_A(1,1);
    if (more){ STAGE_B(1,0,ktn1); STAGE_B(1,1,ktn1); }
    VMW(4);
    PH_MID; MFMA16(1,1); MFMA16(1,0); PH_END;
  }

  int ncol0 = n0 + wn*64;
  if (PASS == 1){
    // staged-LDS coalesced bf16 epilogue (wave-private 16 KB region).
    // Drain + barrier: all waves' loop reads complete before LDS overwrite.
    asm volatile("s_waitcnt lgkmcnt(0)" ::: "memory");
    __builtin_amdgcn_s_barrier();
    unsigned short* Hp = (unsigned short*)outp;
    float* lws = (float*)lds + w * 4096;   // 64 rows x 64 cols f32
    int e = nb*2 + (wn >> 1);              // wave's 64-col range = one expert
    float b1v[4];
    #pragma unroll
    for (int j = 0; j < 4; ++j) b1v[j] = bias[e*H_ + (wn&1)*64 + j*16 + rowi];
    #pragma unroll
    for (int ci = 0; ci < 2; ++ci){
      #pragma unroll
      for (int f2 = 0; f2 < 4; ++f2){
        int fi = ci*4 + f2;
        #pragma unroll
        for (int jj = 0; jj < 4; ++jj){
          int m = m0 + wm*128 + fi*16 + s4*4 + jj;
          float g = gate[(size_t)m*E_ + e];
          int r_l = f2*16 + s4*4 + jj;
          #pragma unroll
          for (int j = 0; j < 4; ++j){
            float v = fmaxf(acc[fi][j][jj] + b1v[j], 0.f) * g;
            lws[r_l*64 + ((j*16 + rowi) ^ (s4 << 4))] = v;
          }
        }
      }
      asm volatile("s_waitcnt lgkmcnt(0)" ::: "memory");
      #pragma unroll
      for (int it2 = 0; it2 < 16; ++it2){
        int r_l = it2*4 + (lane >> 4);
        int c4  = lane & 15;
        int X2  = it2 & 3;                 // == (r_l>>2)&3, uniform per instr
        f32x4 v = *(const f32x4*)&lws[r_l*64 + ((c4*4) ^ (X2 << 4))];
        union { unsigned short us[4]; uint2 u2; } pk;
        #pragma unroll
        for (int q = 0; q < 4; ++q) pk.us[q] = f2bf(v[q]);
        int m = m0 + wm*128 + ci*64 + r_l;
        *(uint2*)&Hp[(size_t)m*N_ + ncol0 + c4*4] = pk.u2;
      }
      if (ci == 0) asm volatile("s_waitcnt lgkmcnt(0)" ::: "memory");
    }
  } else {
    // direct f32 epilogue (64B j-chunks merge into full lines)
    float* Out = (float*)outp;
    float b2v[8][4];
    #pragma unroll
    for (int j = 0; j < 4; ++j){
      int n = ncol0 + j*16 + rowi;
      #pragma unroll
      for (int e = 0; e < 8; ++e) b2v[e][j] = bias[(size_t)e*N_ + n];
    }
    #pragma unroll
    for (int fi = 0; fi < 8; ++fi){
      #pragma unroll
      for (int jj = 0; jj < 4; ++jj){
        int m = m0 + wm*128 + fi*16 + s4*4 + jj;
        const float4 g0 = *(const float4*)(gate + (size_t)m*E_);
        const float4 g1 = *(const float4*)(gate + (size_t)m*E_ + 4);
        float bv[4];
        #pragma unroll
        for (int j = 0; j < 4; ++j)
          bv[j] = g0.x*b2v[0][j] + g0.y*b2v[1][j] + g0.z*b2v[2][j] + g0.w*b2v[3][j]
                + g1.x*b2v[4][j] + g1.y*b2v[5][j] + g1.z*b2v[6][j] + g1.w*b2v[7][j];
        #pragma unroll
        for (int j = 0; j < 4; ++j)
          Out[(size_t)m*N_ + ncol0 + j*16 + rowi] = acc[fi][j][jj] + bv[j];
      }
    }
  }
#undef STAGE_A
#undef STAGE_B
}

// ---------------------------------------------------------------------------
extern "C" void kernel_launch(void* const* d_in, const int* in_sizes, int n_in,
                              void* d_out, int out_size, void* d_ws, size_t ws_size,
                              hipStream_t stream){
  const float* x  = (const float*)d_in[0];
  const float* W1 = (const float*)d_in[1];
  const float* b1 = (const float*)d_in[2];
  const float* W2 = (const float*)d_in[3];
  const float* b2 = (const float*)d_in[4];
  const float* Wg = (const float*)d_in[5];
  const float* bg = (const float*)d_in[6];
  float* out = (float*)d_out;

  char* ws = (char*)d_ws;
  unsigned short* xb  = (unsigned short*)(ws);                         // 32 MB bf16 x
  unsigned short* Hp  = (unsigned short*)(ws + ((size_t)32<<20));      // 32 MB bf16 H'
  unsigned short* B1T = (unsigned short*)(ws + ((size_t)64<<20));      // 2 MB
  unsigned short* B2T = (unsigned short*)(ws + ((size_t)66<<20));      // 2 MB
  float*          gate= (float*)(ws + ((size_t)68<<20));               // 512 KB

  hipLaunchKernelGGL(prep_x_gate, dim3(M_/4), dim3(256), 0, stream, x, Wg, bg, xb, gate);
  hipLaunchKernelGGL(transpose_pack, dim3(128/32, 1024/32, 8), dim3(32,8), 0, stream,
                     W1, B1T, 128, 1024, 1024*128, 128*1024);
  hipLaunchKernelGGL(transpose_pack, dim3(1024/32, 128/32, 8), dim3(32,8), 0, stream,
                     W2, B2T, 1024, 1024, 128*1024, 128);
  hipLaunchKernelGGL((gemm_moe8<1>), dim3(256), dim3(512), 0, stream,
                     xb, B1T, gate, b1, (void*)Hp);
  hipLaunchKernelGGL((gemm_moe8<2>), dim3(256), dim3(512), 0, stream,
                     Hp, B2T, gate, b2, (void*)out);
}

// Round 18
// 104.400 us; speedup vs baseline: 1.0143x; 1.0047x over previous
//
#include <hip/hip_runtime.h>
#include <hip/hip_bf16.h>

// Problem constants
#define B_ 4
#define S_ 4096
#define D_ 1024
#define E_ 8
#define H_ 128
#define M_ (B_*S_)   // 16384 tokens
#define K_ 1024
#define N_ 1024      // E_*H_ == D_ == 1024
#define NT_ (K_/64)  // 16 K-tiles of BK=64
#define NIT_ (NT_/2) // 8 iterations, 2 K-tiles each

typedef short bf16x8 __attribute__((ext_vector_type(8)));
typedef float f32x4 __attribute__((ext_vector_type(4)));

__device__ __forceinline__ unsigned short f2bf(float f){
  union { float f; unsigned int u; } v; v.f = f;
  unsigned int u = v.u;
  unsigned int r = (u + 0x7fffu + ((u >> 16) & 1u)) >> 16;  // RNE
  return (unsigned short)r;
}

__device__ __forceinline__ void gload16(const void* g, void* l){
  __builtin_amdgcn_global_load_lds((const __attribute__((address_space(1))) void*)g,
                                   (__attribute__((address_space(3))) void*)l, 16, 0, 0);
}

// ---------------------------------------------------------------------------
// Kernel 1 (R8-proven): x -> xb (bf16) + gate softmax, 1 token/wave.
// ---------------------------------------------------------------------------
__global__ __launch_bounds__(256)
void prep_x_gate(const float* __restrict__ x, const float* __restrict__ Wg,
                 const float* __restrict__ bg, unsigned short* __restrict__ xb,
                 float* __restrict__ gate){
  int tid = threadIdx.x;
  int lane = tid & 63;
  int m = blockIdx.x * 4 + (tid >> 6);
  const float* xr = x + (size_t)m * D_;
  unsigned short* xbr = xb + (size_t)m * D_;
  float acc[E_];
  #pragma unroll
  for (int e = 0; e < E_; ++e) acc[e] = 0.f;
  #pragma unroll
  for (int c = 0; c < D_/64; ++c){
    int d = c*64 + lane;
    float xs = xr[d];
    xbr[d] = f2bf(xs);
    const float4 w0 = *(const float4*)(Wg + (size_t)d * E_);
    const float4 w1 = *(const float4*)(Wg + (size_t)d * E_ + 4);
    acc[0] = fmaf(xs, w0.x, acc[0]); acc[1] = fmaf(xs, w0.y, acc[1]);
    acc[2] = fmaf(xs, w0.z, acc[2]); acc[3] = fmaf(xs, w0.w, acc[3]);
    acc[4] = fmaf(xs, w1.x, acc[4]); acc[5] = fmaf(xs, w1.y, acc[5]);
    acc[6] = fmaf(xs, w1.z, acc[6]); acc[7] = fmaf(xs, w1.w, acc[7]);
  }
  #pragma unroll
  for (int off = 32; off > 0; off >>= 1){
    #pragma unroll
    for (int e = 0; e < E_; ++e) acc[e] += __shfl_xor(acc[e], off, 64);
  }
  float lg[E_]; float mx = -1e30f;
  #pragma unroll
  for (int e = 0; e < E_; ++e){ lg[e] = acc[e] + bg[e]; mx = fmaxf(mx, lg[e]); }
  float s = 0.f;
  #pragma unroll
  for (int e = 0; e < E_; ++e){ lg[e] = expf(lg[e] - mx); s += lg[e]; }
  float inv = 1.f / s;
  if (lane < E_) gate[(size_t)m * E_ + lane] = lg[lane] * inv;
}

// ---------------------------------------------------------------------------
// Kernel 2: per-expert transpose+pack f32 -> bf16, n-major/k-contiguous.
// ---------------------------------------------------------------------------
__global__ __launch_bounds__(256)
void transpose_pack(const float* __restrict__ in, unsigned short* __restrict__ out,
                    int C, int ostride, int in_estride, int out_ebase){
  __shared__ float t[32][33];
  int e = blockIdx.z;
  const float* ip = in + (size_t)e * in_estride;
  unsigned short* op = out + (size_t)e * out_ebase;
  int tx = threadIdx.x, ty = threadIdx.y;   // 32 x 8
  int c0 = blockIdx.x * 32, r0 = blockIdx.y * 32;
  #pragma unroll
  for (int yy = 0; yy < 32; yy += 8)
    t[ty + yy][tx] = ip[(size_t)(r0 + ty + yy) * C + (c0 + tx)];
  __syncthreads();
  #pragma unroll
  for (int yy = 0; yy < 32; yy += 8)
    op[(size_t)(c0 + ty + yy) * ostride + (r0 + tx)] = f2bf(t[tx][ty + yy]);
}

// ---------------- shared GEMM macros (256x256, BK=64, 8-wave, 8-phase) ------
#define READ_A(b,r) do{ int ab_ = (b)*16384 + abase0; \
  _Pragma("unroll") for (int f2 = 0; f2 < 4; ++f2){ \
    af[f2][0] = *(const bf16x8*)&lds[ab_ + ((r)*4+f2)*1024 + bk0]; \
    af[f2][1] = *(const bf16x8*)&lds[ab_ + ((r)*4+f2)*1024 + bk1]; } }while(0)
#define READ_B(b,c) do{ int bb_ = (b)*16384 + bbase0; \
  _Pragma("unroll") for (int j2 = 0; j2 < 2; ++j2){ \
    bfr[(c)*2+j2][0] = *(const bf16x8*)&lds[bb_ + ((c)*2+j2)*1024 + bk0]; \
    bfr[(c)*2+j2][1] = *(const bf16x8*)&lds[bb_ + ((c)*2+j2)*1024 + bk1]; } }while(0)
#define MFMA16(r,c) do{ \
  _Pragma("unroll") for (int f2 = 0; f2 < 4; ++f2) \
  _Pragma("unroll") for (int j2 = 0; j2 < 2; ++j2){ \
    acc[(r)*4+f2][(c)*2+j2] = __builtin_amdgcn_mfma_f32_16x16x32_bf16(af[f2][0], bfr[(c)*2+j2][0], acc[(r)*4+f2][(c)*2+j2], 0,0,0); \
    acc[(r)*4+f2][(c)*2+j2] = __builtin_amdgcn_mfma_f32_16x16x32_bf16(af[f2][1], bfr[(c)*2+j2][1], acc[(r)*4+f2][(c)*2+j2], 0,0,0); \
  } }while(0)
// ONE barrier per phase; compiler-counted lgkmcnt covers own-wave ds_reads.
#define PH_MID  __builtin_amdgcn_s_barrier(); \
                __builtin_amdgcn_s_setprio(1)
#define PH_END  __builtin_amdgcn_s_setprio(0)
#define VMW(N)  asm volatile("s_waitcnt vmcnt(" #N ")" ::: "memory")

// ---------------------------------------------------------------------------
// Kernel 3: 256x256-tile, BK=64, 8-wave, 8-phase bf16 GEMM (R9 schedule —
// fastest race-class-clean config; every stage >=1 barrier after its region's
// last read, NO same-phase stage/read overlap anywhere; audited per-region:
//   P1.SA(1,1): 2 bars after P7 | P3.SB(0,0): 1 after P2 | P4.SB(0,1): 2
//   P5.SA(0,0): 2 after P3      | P6.SA(0,1): 3          | P7.SB(1,0): 1
//   P8.SA(1,0): 1 after P7      | P8.SB(1,1): 2
// vmcnt ledger: prologue t0 full + t1{B,Ah0}, VMW(6) pubs buf0;
// P4: VMW(4) [final iter VMW(0)] pubs buf1; P8: VMW(6) pubs buf0.)
// PASS 1: staged-LDS coalesced bf16 epilogue, gate*relu(acc+b1).
// PASS 2: direct f32 stores, acc + sum_e gate_e*b2[e][d].
// ---------------------------------------------------------------------------
template<int PASS>
__global__ __launch_bounds__(512, 2)
void gemm_moe8(const unsigned short* __restrict__ A,
               const unsigned short* __restrict__ Bt,
               const float* __restrict__ gate,
               const float* __restrict__ bias,
               void* __restrict__ outp)
{
  __shared__ unsigned short lds[65536];   // 128 KiB

  int bid = blockIdx.x;
  int xcd = bid & 7, pos = bid >> 3;
  int mb = xcd * 8 + (pos >> 2);
  int nb = pos & 3;
  int m0 = mb * 256, n0 = nb * 256;

  int tid = threadIdx.x;
  int lane = tid & 63;
  int w = tid >> 6;
  int wm = w & 1, wn = w >> 1;            // 2x4 wave grid; wave owns 128x64
  int rowi = lane & 15, s4 = lane >> 4;

  // staging addresses (linear LDS dest; swizzled global source)
  int sg = (tid & 7) ^ ((tid >> 3) & 7);
  const unsigned short* gA = A  + (size_t)(m0 + (tid >> 3)) * K_ + sg * 8;
  const unsigned short* gB = Bt + (size_t)(n0 + (tid >> 3)) * K_ + sg * 8;
  int t8 = tid * 8;

#define STAGE_A(b,h,kt) do{ const unsigned short* g_ = gA + (size_t)((h)*128)*K_ + (kt)*64; \
  gload16(g_,                 &lds[(b)*16384 + (h)*8192 + t8]); \
  gload16(g_ + (size_t)64*K_, &lds[(b)*16384 + (h)*8192 + t8 + 4096]); }while(0)
#define STAGE_B(b,h,kt) do{ const unsigned short* g_ = gB + (size_t)((h)*128)*K_ + (kt)*64; \
  gload16(g_,                 &lds[32768 + (b)*16384 + (h)*8192 + t8]); \
  gload16(g_ + (size_t)64*K_, &lds[32768 + (b)*16384 + (h)*8192 + t8 + 4096]); }while(0)

  // read-side fragment offsets (same XOR on the slot)
  int bk0 = rowi*64 + (( s4     ) ^ (rowi & 7)) * 8;
  int bk1 = rowi*64 + ((4 + s4  ) ^ (rowi & 7)) * 8;
  int abase0 = wm * 8192;
  int bbase0 = 32768 + (wn >> 1) * 8192 + (wn & 1) * 4096;

  f32x4 acc[8][4];
  #pragma unroll
  for (int i = 0; i < 8; ++i){
    #pragma unroll
    for (int j = 0; j < 4; ++j){ f32x4 z = {0.f,0.f,0.f,0.f}; acc[i][j] = z; }
  }
  bf16x8 af[4][2], bfr[4][2];

  // prologue: tile0 full; tile1 {Bh0,Bh1,Ah0} in flight (counted wait)
  STAGE_B(0,0,0); STAGE_B(0,1,0);
  STAGE_A(0,0,0); STAGE_A(0,1,0);
  STAGE_B(1,0,1); STAGE_B(1,1,1);
  STAGE_A(1,0,1);
  VMW(6);
  __builtin_amdgcn_s_barrier();           // publishes buf0

  #pragma unroll 1
  for (int it = 0; it < NIT_; ++it){
    int kt1  = 2*it + 1;
    int ktn0 = 2*it + 2, ktn1 = 2*it + 3;
    bool more = (it < NIT_ - 1);
    // P1
    READ_A(0,0); READ_B(0,0);
    STAGE_A(1,1,kt1);
    PH_MID; MFMA16(0,0); PH_END;
    // P2
    READ_B(0,1);
    PH_MID; MFMA16(0,1); PH_END;
    // P3
    READ_A(0,1);
    if (more) STAGE_B(0,0,ktn0);
    PH_MID; MFMA16(1,1); PH_END;
    // P4  (vm wait pre-barrier: barrier(P4) publishes buf1 for P5 reads)
    if (more){ STAGE_B(0,1,ktn0); VMW(4); }
    else     { VMW(0); }                  // final tile's A halves must land
    PH_MID; MFMA16(1,0); PH_END;
    // P5
    READ_A(1,0); READ_B(1,0);
    if (more) STAGE_A(0,0,ktn0);
    PH_MID; MFMA16(0,0); PH_END;
    // P6
    READ_B(1,1);
    if (more) STAGE_A(0,1,ktn0);
    PH_MID; MFMA16(0,1); PH_END;
    // P7
    READ_A(1,1);
    if (more) STAGE_B(1,0,ktn1);
    PH_MID; MFMA16(1,1); PH_END;
    // P8  (vm(6) pre-barrier: barrier(P8) publishes buf0 for next P1)
    if (more){ STAGE_B(1,1,ktn1); STAGE_A(1,0,ktn1); }
    VMW(6);
    PH_MID; MFMA16(1,0); PH_END;
  }

  int ncol0 = n0 + wn*64;
  if (PASS == 1){
    // staged-LDS coalesced bf16 epilogue (wave-private 16 KB region).
    // Drain + barrier: all waves' loop ds_reads complete before LDS overwrite.
    asm volatile("s_waitcnt lgkmcnt(0)" ::: "memory");
    __builtin_amdgcn_s_barrier();
    unsigned short* Hp = (unsigned short*)outp;
    float* lws = (float*)lds + w * 4096;   // 64 rows x 64 cols f32
    int e = nb*2 + (wn >> 1);              // wave's 64-col range = one expert
    float b1v[4];
    #pragma unroll
    for (int j = 0; j < 4; ++j) b1v[j] = bias[e*H_ + (wn&1)*64 + j*16 + rowi];
    #pragma unroll
    for (int ci = 0; ci < 2; ++ci){
      #pragma unroll
      for (int f2 = 0; f2 < 4; ++f2){
        int fi = ci*4 + f2;
        #pragma unroll
        for (int jj = 0; jj < 4; ++jj){
          int m = m0 + wm*128 + fi*16 + s4*4 + jj;
          float g = gate[(size_t)m*E_ + e];
          int r_l = f2*16 + s4*4 + jj;
          #pragma unroll
          for (int j = 0; j < 4; ++j){
            float v = fmaxf(acc[fi][j][jj] + b1v[j], 0.f) * g;
            lws[r_l*64 + ((j*16 + rowi) ^ (s4 << 4))] = v;
          }
        }
      }
      asm volatile("s_waitcnt lgkmcnt(0)" ::: "memory");
      #pragma unroll
      for (int it2 = 0; it2 < 16; ++it2){
        int r_l = it2*4 + (lane >> 4);
        int c4  = lane & 15;
        int X2  = it2 & 3;                 // == (r_l>>2)&3, uniform per instr
        f32x4 v = *(const f32x4*)&lws[r_l*64 + ((c4*4) ^ (X2 << 4))];
        union { unsigned short us[4]; uint2 u2; } pk;
        #pragma unroll
        for (int q = 0; q < 4; ++q) pk.us[q] = f2bf(v[q]);
        int m = m0 + wm*128 + ci*64 + r_l;
        *(uint2*)&Hp[(size_t)m*N_ + ncol0 + c4*4] = pk.u2;
      }
      if (ci == 0) asm volatile("s_waitcnt lgkmcnt(0)" ::: "memory");
    }
  } else {
    // direct f32 epilogue (64B j-chunks merge into full lines)
    float* Out = (float*)outp;
    float b2v[8][4];
    #pragma unroll
    for (int j = 0; j < 4; ++j){
      int n = ncol0 + j*16 + rowi;
      #pragma unroll
      for (int e = 0; e < 8; ++e) b2v[e][j] = bias[(size_t)e*N_ + n];
    }
    #pragma unroll
    for (int fi = 0; fi < 8; ++fi){
      #pragma unroll
      for (int jj = 0; jj < 4; ++jj){
        int m = m0 + wm*128 + fi*16 + s4*4 + jj;
        const float4 g0 = *(const float4*)(gate + (size_t)m*E_);
        const float4 g1 = *(const float4*)(gate + (size_t)m*E_ + 4);
        float bv[4];
        #pragma unroll
        for (int j = 0; j < 4; ++j)
          bv[j] = g0.x*b2v[0][j] + g0.y*b2v[1][j] + g0.z*b2v[2][j] + g0.w*b2v[3][j]
                + g1.x*b2v[4][j] + g1.y*b2v[5][j] + g1.z*b2v[6][j] + g1.w*b2v[7][j];
        #pragma unroll
        for (int j = 0; j < 4; ++j)
          Out[(size_t)m*N_ + ncol0 + j*16 + rowi] = acc[fi][j][jj] + bv[j];
      }
    }
  }
#undef STAGE_A
#undef STAGE_B
}

// ---------------------------------------------------------------------------
extern "C" void kernel_launch(void* const* d_in, const int* in_sizes, int n_in,
                              void* d_out, int out_size, void* d_ws, size_t ws_size,
                              hipStream_t stream){
  const float* x  = (const float*)d_in[0];
  const float* W1 = (const float*)d_in[1];
  const float* b1 = (const float*)d_in[2];
  const float* W2 = (const float*)d_in[3];
  const float* b2 = (const float*)d_in[4];
  const float* Wg = (const float*)d_in[5];
  const float* bg = (const float*)d_in[6];
  float* out = (float*)d_out;

  char* ws = (char*)d_ws;
  unsigned short* xb  = (unsigned short*)(ws);                         // 32 MB bf16 x
  unsigned short* Hp  = (unsigned short*)(ws + ((size_t)32<<20));      // 32 MB bf16 H'
  unsigned short* B1T = (unsigned short*)(ws + ((size_t)64<<20));      // 2 MB
  unsigned short* B2T = (unsigned short*)(ws + ((size_t)66<<20));      // 2 MB
  float*          gate= (float*)(ws + ((size_t)68<<20));               // 512 KB

  hipLaunchKernelGGL(prep_x_gate, dim3(M_/4), dim3(256), 0, stream, x, Wg, bg, xb, gate);
  hipLaunchKernelGGL(transpose_pack, dim3(128/32, 1024/32, 8), dim3(32,8), 0, stream,
                     W1, B1T, 128, 1024, 1024*128, 128*1024);
  hipLaunchKernelGGL(transpose_pack, dim3(1024/32, 128/32, 8), dim3(32,8), 0, stream,
                     W2, B2T, 1024, 1024, 128*1024, 128);
  hipLaunchKernelGGL((gemm_moe8<1>), dim3(256), dim3(512), 0, stream,
                     xb, B1T, gate, b1, (void*)Hp);
  hipLaunchKernelGGL((gemm_moe8<2>), dim3(256), dim3(512), 0, stream,
                     Hp, B2T, gate, b2, (void*)out);
}

// Round 19
// 101.095 us; speedup vs baseline: 1.0474x; 1.0327x over previous
//
#include <hip/hip_runtime.h>
#include <hip/hip_bf16.h>

// Problem constants
#define B_ 4
#define S_ 4096
#define D_ 1024
#define E_ 8
#define H_ 128
#define M_ (B_*S_)   // 16384 tokens
#define K_ 1024
#define N_ 1024      // E_*H_ == D_ == 1024
#define NT_ (K_/64)  // 16 K-tiles of BK=64
#define NIT_ (NT_/2) // 8 iterations, 2 K-tiles each

typedef short bf16x8 __attribute__((ext_vector_type(8)));
typedef float f32x4 __attribute__((ext_vector_type(4)));

__device__ __forceinline__ unsigned short f2bf(float f){
  union { float f; unsigned int u; } v; v.f = f;
  unsigned int u = v.u;
  unsigned int r = (u + 0x7fffu + ((u >> 16) & 1u)) >> 16;  // RNE
  return (unsigned short)r;
}

__device__ __forceinline__ void gload16(const void* g, void* l){
  __builtin_amdgcn_global_load_lds((const __attribute__((address_space(1))) void*)g,
                                   (__attribute__((address_space(3))) void*)l, 16, 0, 0);
}

// ---------------------------------------------------------------------------
// Kernel 1 (R8-proven): x -> xb (bf16) + gate softmax, 1 token/wave.
// ---------------------------------------------------------------------------
__global__ __launch_bounds__(256)
void prep_x_gate(const float* __restrict__ x, const float* __restrict__ Wg,
                 const float* __restrict__ bg, unsigned short* __restrict__ xb,
                 float* __restrict__ gate){
  int tid = threadIdx.x;
  int lane = tid & 63;
  int m = blockIdx.x * 4 + (tid >> 6);
  const float* xr = x + (size_t)m * D_;
  unsigned short* xbr = xb + (size_t)m * D_;
  float acc[E_];
  #pragma unroll
  for (int e = 0; e < E_; ++e) acc[e] = 0.f;
  #pragma unroll
  for (int c = 0; c < D_/64; ++c){
    int d = c*64 + lane;
    float xs = xr[d];
    xbr[d] = f2bf(xs);
    const float4 w0 = *(const float4*)(Wg + (size_t)d * E_);
    const float4 w1 = *(const float4*)(Wg + (size_t)d * E_ + 4);
    acc[0] = fmaf(xs, w0.x, acc[0]); acc[1] = fmaf(xs, w0.y, acc[1]);
    acc[2] = fmaf(xs, w0.z, acc[2]); acc[3] = fmaf(xs, w0.w, acc[3]);
    acc[4] = fmaf(xs, w1.x, acc[4]); acc[5] = fmaf(xs, w1.y, acc[5]);
    acc[6] = fmaf(xs, w1.z, acc[6]); acc[7] = fmaf(xs, w1.w, acc[7]);
  }
  #pragma unroll
  for (int off = 32; off > 0; off >>= 1){
    #pragma unroll
    for (int e = 0; e < E_; ++e) acc[e] += __shfl_xor(acc[e], off, 64);
  }
  float lg[E_]; float mx = -1e30f;
  #pragma unroll
  for (int e = 0; e < E_; ++e){ lg[e] = acc[e] + bg[e]; mx = fmaxf(mx, lg[e]); }
  float s = 0.f;
  #pragma unroll
  for (int e = 0; e < E_; ++e){ lg[e] = expf(lg[e] - mx); s += lg[e]; }
  float inv = 1.f / s;
  if (lane < E_) gate[(size_t)m * E_ + lane] = lg[lane] * inv;
}

// ---------------------------------------------------------------------------
// Kernel 2: per-expert transpose+pack f32 -> bf16, n-major/k-contiguous.
// ---------------------------------------------------------------------------
__global__ __launch_bounds__(256)
void transpose_pack(const float* __restrict__ in, unsigned short* __restrict__ out,
                    int C, int ostride, int in_estride, int out_ebase){
  __shared__ float t[32][33];
  int e = blockIdx.z;
  const float* ip = in + (size_t)e * in_estride;
  unsigned short* op = out + (size_t)e * out_ebase;
  int tx = threadIdx.x, ty = threadIdx.y;   // 32 x 8
  int c0 = blockIdx.x * 32, r0 = blockIdx.y * 32;
  #pragma unroll
  for (int yy = 0; yy < 32; yy += 8)
    t[ty + yy][tx] = ip[(size_t)(r0 + ty + yy) * C + (c0 + tx)];
  __syncthreads();
  #pragma unroll
  for (int yy = 0; yy < 32; yy += 8)
    op[(size_t)(c0 + ty + yy) * ostride + (r0 + tx)] = f2bf(t[tx][ty + yy]);
}

// ---------------- shared GEMM macros (256x256, BK=64, 8-wave, 8-phase) ------
#define READ_A(b,r) do{ int ab_ = (b)*16384 + abase0; \
  _Pragma("unroll") for (int f2 = 0; f2 < 4; ++f2){ \
    af[f2][0] = *(const bf16x8*)&lds[ab_ + ((r)*4+f2)*1024 + bk0]; \
    af[f2][1] = *(const bf16x8*)&lds[ab_ + ((r)*4+f2)*1024 + bk1]; } }while(0)
#define READ_B(b,c) do{ int bb_ = (b)*16384 + bbase0; \
  _Pragma("unroll") for (int j2 = 0; j2 < 2; ++j2){ \
    bfr[(c)*2+j2][0] = *(const bf16x8*)&lds[bb_ + ((c)*2+j2)*1024 + bk0]; \
    bfr[(c)*2+j2][1] = *(const bf16x8*)&lds[bb_ + ((c)*2+j2)*1024 + bk1]; } }while(0)
#define MFMA16(r,c) do{ \
  _Pragma("unroll") for (int f2 = 0; f2 < 4; ++f2) \
  _Pragma("unroll") for (int j2 = 0; j2 < 2; ++j2){ \
    acc[(r)*4+f2][(c)*2+j2] = __builtin_amdgcn_mfma_f32_16x16x32_bf16(af[f2][0], bfr[(c)*2+j2][0], acc[(r)*4+f2][(c)*2+j2], 0,0,0); \
    acc[(r)*4+f2][(c)*2+j2] = __builtin_amdgcn_mfma_f32_16x16x32_bf16(af[f2][1], bfr[(c)*2+j2][1], acc[(r)*4+f2][(c)*2+j2], 0,0,0); \
  } }while(0)
// ONE barrier per phase; compiler-counted lgkmcnt covers own-wave ds_reads.
#define PH_MID  __builtin_amdgcn_s_barrier(); \
                __builtin_amdgcn_s_setprio(1)
#define PH_END  __builtin_amdgcn_s_setprio(0)
#define VMW(N)  asm volatile("s_waitcnt vmcnt(" #N ")" ::: "memory")

// ---------------------------------------------------------------------------
// Kernel 3: 256x256-tile, BK=64, 8-wave, 8-phase bf16 GEMM (R9 schedule —
// fastest measured AND race-class-clean: every stage issues >=1 barrier after
// its region's last read; no same-phase stage/read overlap anywhere.
// Safety: a phase's ds_reads are register-consumed by the MFMA right after
// their barrier (~120cy), while any overwriting DMA issues after that barrier
// and lands >=300cy later — positive margin by construction. (The 4-phase
// variants R11-R16 broke this with a same-phase window; reverted.)
// vmcnt ledger: prologue t0 full + t1{B,Ah0}, VMW(6) pubs buf0;
// P4: VMW(4) [final iter VMW(0)] pubs buf1; P8: VMW(6) pubs buf0.
// Epilogue: at the pass-1 barrier all waves' loop reads are already
// register-consumed, so no extra drain is required before LDS reuse.
// PASS 1: staged-LDS coalesced bf16 epilogue, gate*relu(acc+b1).
// PASS 2: direct f32 stores, acc + sum_e gate_e*b2[e][d].
// ---------------------------------------------------------------------------
template<int PASS>
__global__ __launch_bounds__(512, 2)
void gemm_moe8(const unsigned short* __restrict__ A,
               const unsigned short* __restrict__ Bt,
               const float* __restrict__ gate,
               const float* __restrict__ bias,
               void* __restrict__ outp)
{
  __shared__ unsigned short lds[65536];   // 128 KiB

  int bid = blockIdx.x;
  int xcd = bid & 7, pos = bid >> 3;
  int mb = xcd * 8 + (pos >> 2);
  int nb = pos & 3;
  int m0 = mb * 256, n0 = nb * 256;

  int tid = threadIdx.x;
  int lane = tid & 63;
  int w = tid >> 6;
  int wm = w & 1, wn = w >> 1;            // 2x4 wave grid; wave owns 128x64
  int rowi = lane & 15, s4 = lane >> 4;

  // staging addresses (linear LDS dest; swizzled global source)
  int sg = (tid & 7) ^ ((tid >> 3) & 7);
  const unsigned short* gA = A  + (size_t)(m0 + (tid >> 3)) * K_ + sg * 8;
  const unsigned short* gB = Bt + (size_t)(n0 + (tid >> 3)) * K_ + sg * 8;
  int t8 = tid * 8;

#define STAGE_A(b,h,kt) do{ const unsigned short* g_ = gA + (size_t)((h)*128)*K_ + (kt)*64; \
  gload16(g_,                 &lds[(b)*16384 + (h)*8192 + t8]); \
  gload16(g_ + (size_t)64*K_, &lds[(b)*16384 + (h)*8192 + t8 + 4096]); }while(0)
#define STAGE_B(b,h,kt) do{ const unsigned short* g_ = gB + (size_t)((h)*128)*K_ + (kt)*64; \
  gload16(g_,                 &lds[32768 + (b)*16384 + (h)*8192 + t8]); \
  gload16(g_ + (size_t)64*K_, &lds[32768 + (b)*16384 + (h)*8192 + t8 + 4096]); }while(0)

  // read-side fragment offsets (same XOR on the slot)
  int bk0 = rowi*64 + (( s4     ) ^ (rowi & 7)) * 8;
  int bk1 = rowi*64 + ((4 + s4  ) ^ (rowi & 7)) * 8;
  int abase0 = wm * 8192;
  int bbase0 = 32768 + (wn >> 1) * 8192 + (wn & 1) * 4096;

  f32x4 acc[8][4];
  #pragma unroll
  for (int i = 0; i < 8; ++i){
    #pragma unroll
    for (int j = 0; j < 4; ++j){ f32x4 z = {0.f,0.f,0.f,0.f}; acc[i][j] = z; }
  }
  bf16x8 af[4][2], bfr[4][2];

  // prologue: tile0 full; tile1 {Bh0,Bh1,Ah0} in flight (counted wait)
  STAGE_B(0,0,0); STAGE_B(0,1,0);
  STAGE_A(0,0,0); STAGE_A(0,1,0);
  STAGE_B(1,0,1); STAGE_B(1,1,1);
  STAGE_A(1,0,1);
  VMW(6);
  __builtin_amdgcn_s_barrier();           // publishes buf0

  #pragma unroll 1
  for (int it = 0; it < NIT_; ++it){
    int kt1  = 2*it + 1;
    int ktn0 = 2*it + 2, ktn1 = 2*it + 3;
    bool more = (it < NIT_ - 1);
    // P1
    READ_A(0,0); READ_B(0,0);
    STAGE_A(1,1,kt1);
    PH_MID; MFMA16(0,0); PH_END;
    // P2
    READ_B(0,1);
    PH_MID; MFMA16(0,1); PH_END;
    // P3
    READ_A(0,1);
    if (more) STAGE_B(0,0,ktn0);
    PH_MID; MFMA16(1,1); PH_END;
    // P4  (vm wait pre-barrier: barrier(P4) publishes buf1 for P5 reads)
    if (more){ STAGE_B(0,1,ktn0); VMW(4); }
    else     { VMW(0); }                  // final tile's A halves must land
    PH_MID; MFMA16(1,0); PH_END;
    // P5
    READ_A(1,0); READ_B(1,0);
    if (more) STAGE_A(0,0,ktn0);
    PH_MID; MFMA16(0,0); PH_END;
    // P6
    READ_B(1,1);
    if (more) STAGE_A(0,1,ktn0);
    PH_MID; MFMA16(0,1); PH_END;
    // P7
    READ_A(1,1);
    if (more) STAGE_B(1,0,ktn1);
    PH_MID; MFMA16(1,1); PH_END;
    // P8  (vm(6) pre-barrier: barrier(P8) publishes buf0 for next P1)
    if (more){ STAGE_B(1,1,ktn1); STAGE_A(1,0,ktn1); }
    VMW(6);
    PH_MID; MFMA16(1,0); PH_END;
  }

  int ncol0 = n0 + wn*64;
  if (PASS == 1){
    // staged-LDS coalesced bf16 epilogue (wave-private 16 KB region).
    // Barrier: waves' loop reads are register-consumed before arriving here.
    __builtin_amdgcn_s_barrier();
    unsigned short* Hp = (unsigned short*)outp;
    float* lws = (float*)lds + w * 4096;   // 64 rows x 64 cols f32
    int e = nb*2 + (wn >> 1);              // wave's 64-col range = one expert
    float b1v[4];
    #pragma unroll
    for (int j = 0; j < 4; ++j) b1v[j] = bias[e*H_ + (wn&1)*64 + j*16 + rowi];
    #pragma unroll
    for (int ci = 0; ci < 2; ++ci){
      #pragma unroll
      for (int f2 = 0; f2 < 4; ++f2){
        int fi = ci*4 + f2;
        #pragma unroll
        for (int jj = 0; jj < 4; ++jj){
          int m = m0 + wm*128 + fi*16 + s4*4 + jj;
          float g = gate[(size_t)m*E_ + e];
          int r_l = f2*16 + s4*4 + jj;
          #pragma unroll
          for (int j = 0; j < 4; ++j){
            float v = fmaxf(acc[fi][j][jj] + b1v[j], 0.f) * g;
            lws[r_l*64 + ((j*16 + rowi) ^ (s4 << 4))] = v;
          }
        }
      }
      asm volatile("s_waitcnt lgkmcnt(0)" ::: "memory");
      #pragma unroll
      for (int it2 = 0; it2 < 16; ++it2){
        int r_l = it2*4 + (lane >> 4);
        int c4  = lane & 15;
        int X2  = it2 & 3;                 // == (r_l>>2)&3, uniform per instr
        f32x4 v = *(const f32x4*)&lws[r_l*64 + ((c4*4) ^ (X2 << 4))];
        union { unsigned short us[4]; uint2 u2; } pk;
        #pragma unroll
        for (int q = 0; q < 4; ++q) pk.us[q] = f2bf(v[q]);
        int m = m0 + wm*128 + ci*64 + r_l;
        *(uint2*)&Hp[(size_t)m*N_ + ncol0 + c4*4] = pk.u2;
      }
      if (ci == 0) asm volatile("s_waitcnt lgkmcnt(0)" ::: "memory");
    }
  } else {
    // direct f32 epilogue (64B j-chunks merge into full lines)
    float* Out = (float*)outp;
    float b2v[8][4];
    #pragma unroll
    for (int j = 0; j < 4; ++j){
      int n = ncol0 + j*16 + rowi;
      #pragma unroll
      for (int e = 0; e < 8; ++e) b2v[e][j] = bias[(size_t)e*N_ + n];
    }
    #pragma unroll
    for (int fi = 0; fi < 8; ++fi){
      #pragma unroll
      for (int jj = 0; jj < 4; ++jj){
        int m = m0 + wm*128 + fi*16 + s4*4 + jj;
        const float4 g0 = *(const float4*)(gate + (size_t)m*E_);
        const float4 g1 = *(const float4*)(gate + (size_t)m*E_ + 4);
        float bv[4];
        #pragma unroll
        for (int j = 0; j < 4; ++j)
          bv[j] = g0.x*b2v[0][j] + g0.y*b2v[1][j] + g0.z*b2v[2][j] + g0.w*b2v[3][j]
                + g1.x*b2v[4][j] + g1.y*b2v[5][j] + g1.z*b2v[6][j] + g1.w*b2v[7][j];
        #pragma unroll
        for (int j = 0; j < 4; ++j)
          Out[(size_t)m*N_ + ncol0 + j*16 + rowi] = acc[fi][j][jj] + bv[j];
      }
    }
  }
#undef STAGE_A
#undef STAGE_B
}

// ---------------------------------------------------------------------------
extern "C" void kernel_launch(void* const* d_in, const int* in_sizes, int n_in,
                              void* d_out, int out_size, void* d_ws, size_t ws_size,
                              hipStream_t stream){
  const float* x  = (const float*)d_in[0];
  const float* W1 = (const float*)d_in[1];
  const float* b1 = (const float*)d_in[2];
  const float* W2 = (const float*)d_in[3];
  const float* b2 = (const float*)d_in[4];
  const float* Wg = (const float*)d_in[5];
  const float* bg = (const float*)d_in[6];
  float* out = (float*)d_out;

  char* ws = (char*)d_ws;
  unsigned short* xb  = (unsigned short*)(ws);                         // 32 MB bf16 x
  unsigned short* Hp  = (unsigned short*)(ws + ((size_t)32<<20));      // 32 MB bf16 H'
  unsigned short* B1T = (unsigned short*)(ws + ((size_t)64<<20));      // 2 MB
  unsigned short* B2T = (unsigned short*)(ws + ((size_t)66<<20));      // 2 MB
  float*          gate= (float*)(ws + ((size_t)68<<20));               // 512 KB

  hipLaunchKernelGGL(prep_x_gate, dim3(M_/4), dim3(256), 0, stream, x, Wg, bg, xb, gate);
  hipLaunchKernelGGL(transpose_pack, dim3(128/32, 1024/32, 8), dim3(32,8), 0, stream,
                     W1, B1T, 128, 1024, 1024*128, 128*1024);
  hipLaunchKernelGGL(transpose_pack, dim3(1024/32, 128/32, 8), dim3(32,8), 0, stream,
                     W2, B2T, 1024, 1024, 128*1024, 128);
  hipLaunchKernelGGL((gemm_moe8<1>), dim3(256), dim3(512), 0, stream,
                     xb, B1T, gate, b1, (void*)Hp);
  hipLaunchKernelGGL((gemm_moe8<2>), dim3(256), dim3(512), 0, stream,
                     Hp, B2T, gate, b2, (void*)out);
}